// Round 6
// baseline (77.841 us; speedup 1.0000x reference)
//
#include <hip/hip_runtime.h>
#include <stdint.h>

#define Bn 8
#define Nn 2000
#define Cc 81
#define META_STRIDE (12 + Cc)
#define MAXI 100
#define MINCONF 0.7f
#define NMSTHR 0.3f
#define NPAD 2048
#define NW 32        // 64-bit words per mask row (2048 bits)
#define PB_ROIS 128  // ROIs per k_prep block (16000 / 128 = 125 blocks)
#define PSTRIDE 83   // LDS row stride (81 + 2 pad); 83%32=19, gcd(19,32)=1

// map float to monotonically ordered uint (descending float == descending uint)
__device__ __forceinline__ uint32_t ford(float f) {
    uint32_t u = __float_as_uint(f);
    return (u & 0x80000000u) ? ~u : (u | 0x80000000u);
}

// ---------------- Kernel 1: LDS-staged argmax, delta apply, clip, sort key --
// Stage 128 probs rows into LDS with coalesced loads; 2 threads per row do the
// argmax (halves [0,41)/[41,81), strict > within half, tie -> lower half ==
// JAX first-max). Even thread of each pair does the float4 gather/refine/write.
__global__ void __launch_bounds__(256)
k_prep(const float* __restrict__ rois,
       const float* __restrict__ probs,
       const float* __restrict__ bbox,
       const float* __restrict__ meta,
       float* __restrict__ refined,
       float* __restrict__ score,
       int* __restrict__ cls,
       unsigned long long* __restrict__ keys) {
    __shared__ float sp[PB_ROIS * PSTRIDE];   // 42.5 KB
    int tid  = threadIdx.x;
    int base = blockIdx.x * PB_ROIS;          // global ROI base for this block

    // ---- stage: coalesced global -> LDS (rows packed at stride PSTRIDE) ----
    const float* gp = probs + (size_t)base * Cc;
    const int total = PB_ROIS * Cc;           // 10368
    int r = tid / Cc, c = tid - r * Cc;       // walk (r,c) with idx in lockstep
    for (int idx = tid; idx < total; idx += 256) {
        sp[r * PSTRIDE + c] = gp[idx];
        r += 3; c += 13;                      // 256 = 3*81 + 13
        if (c >= Cc) { c -= Cc; r += 1; }
    }
    __syncthreads();

    // ---- argmax: 2 threads per row ----
    int row  = tid >> 1;
    int half = tid & 1;
    const float* sr = sp + row * PSTRIDE;
    int   c0 = half ? 41 : 0;
    int   c1 = half ? Cc : 41;
    float v  = sr[c0];
    int   cb = c0;
    for (int cc2 = c0 + 1; cc2 < c1; ++cc2) {
        float x = sr[cc2];
        if (x > v) { v = x; cb = cc2; }       // first max wins within half
    }
    float vo = __shfl_xor(v, 1, 64);
    int   co = __shfl_xor(cb, 1, 64);
    float vA = half ? vo : v;   int cA = half ? co : cb;   // low half
    float vB = half ? v  : vo;  int cB = half ? cb : co;   // high half
    float sbest;  int cbest;
    if (vB > vA) { sbest = vB; cbest = cB; }  // tie -> low half (lower index)
    else         { sbest = vA; cbest = cA; }

    if (half) return;                         // even thread per row continues
    int t = base + row;

    // ---- delta gather (one dwordx4; (t*81+cbest)*4 floats is 16B-aligned) --
    float4 d4 = reinterpret_cast<const float4*>(bbox)[(size_t)t * Cc + cbest];
    float dy = d4.x * 0.1f, dx = d4.y * 0.1f, dh = d4.z * 0.2f, dw = d4.w * 0.2f;

    float4 r4 = reinterpret_cast<const float4*>(rois)[t];
    float y1 = r4.x, x1 = r4.y, y2 = r4.z, x2 = r4.w;
    float h = y2 - y1, w = x2 - x1;
    float cy = y1 + 0.5f * h + dy * h;
    float cx = x1 + 0.5f * w + dx * w;
    h = h * expf(dh);
    w = w * expf(dw);
    float ny1 = cy - 0.5f * h, nx1 = cx - 0.5f * w;
    float ny2 = cy + 0.5f * h, nx2 = cx + 0.5f * w;

    // window = (meta[b,7:11] - [0,0,1,1]) / ([h,w,h,w]-1), image shape row 0
    int b = t / Nn;
    float sy = meta[4] - 1.0f, sx = meta[5] - 1.0f;
    const float* mb = meta + (size_t)b * META_STRIDE;
    float wy1 = mb[7] / sy;
    float wx1 = mb[8] / sx;
    float wy2 = (mb[9]  - 1.0f) / sy;
    float wx2 = (mb[10] - 1.0f) / sx;

    ny1 = fminf(fmaxf(ny1, wy1), wy2);
    nx1 = fminf(fmaxf(nx1, wx1), wx2);
    ny2 = fminf(fmaxf(ny2, wy1), wy2);
    nx2 = fminf(fmaxf(nx2, wx1), wx2);

    reinterpret_cast<float4*>(refined)[t] = float4{ny1, nx1, ny2, nx2};
    score[t] = sbest;
    cls[t]   = cbest;

    int i = t - b * Nn;
    bool valid = (cbest > 0) && (sbest >= MINCONF);
    float ks = valid ? sbest : -1.0f;
    keys[t] = ((unsigned long long)ford(ks) << 32) |
              (unsigned long long)(0xFFFFFFFFu - (uint32_t)i);
}

// ---------------- Kernel 2: per-batch bitonic sort (desc), V, sorted boxes --
__global__ void __launch_bounds__(1024, 1)
k_sort(const unsigned long long* __restrict__ keys,
       const float* __restrict__ refined,
       const int* __restrict__ cls,
       uint32_t* __restrict__ sidx,
       float* __restrict__ sbox,
       int* __restrict__ Vout) {
    __shared__ unsigned long long sk[NPAD];
    __shared__ int sV;
    int b = blockIdx.x, tid = threadIdx.x;

    const unsigned long long* kb = keys + (size_t)b * Nn;
    for (int t = tid; t < NPAD; t += 1024)
        sk[t] = (t < Nn) ? kb[t] : 0ull;      // pads sort to the very end
    if (tid == 0) sV = 0;
    __syncthreads();

    for (int k = 2; k <= NPAD; k <<= 1) {
        for (int j = k >> 1; j > 0; j >>= 1) {
            for (int t = tid; t < NPAD; t += 1024) {
                int ixj = t ^ j;
                if (ixj > t) {
                    unsigned long long a = sk[t], c = sk[ixj];
                    bool desc = ((t & k) == 0);
                    if (desc ? (a < c) : (a > c)) { sk[t] = c; sk[ixj] = a; }
                }
            }
            __syncthreads();
        }
    }

    // valid entries (top bit set: score>=0.7>0) form a prefix; find its length
    for (int t = tid; t < Nn; t += 1024) {
        bool v0 = (sk[t] >> 63) != 0ull;
        bool v1 = (t + 1 < Nn) ? ((sk[t + 1] >> 63) != 0ull) : false;
        if (v0 && !v1) sV = t + 1;            // single boundary -> single writer
    }
    __syncthreads();
    if (tid == 0) Vout[b] = sV;

    for (int t = tid; t < Nn; t += 1024) {
        uint32_t oi = 0xFFFFFFFFu - (uint32_t)(sk[t] & 0xFFFFFFFFull);
        sidx[b * Nn + t] = oi;
        int gi = b * Nn + (int)oi;
        float off = 4.0f * (float)cls[gi];    // CLASS_OFFSET * class_id
        float4 rf = reinterpret_cast<const float4*>(refined)[gi];
        reinterpret_cast<float4*>(sbox)[b * Nn + t] =
            float4{rf.x + off, rf.y + off, rf.z + off, rf.w + off};
    }
}

// ---------------- Kernel 3: IoU suppression bitmask rows, one wave per row --
// Row i word w bit l = 1  <=>  j = w*64+l, j > i, j < V, IoU(i,j) > thr.
// Word i>>6 is the "diagonal" word: intra-block suppression bits.
__global__ void k_iou(const float* __restrict__ sbox,
                      const int* __restrict__ Vbuf,
                      unsigned long long* __restrict__ mask) {
    int gt   = blockIdx.x * blockDim.x + threadIdx.x;
    int wid  = gt >> 6;
    int lane = threadIdx.x & 63;
    if (wid >= Bn * Nn) return;
    int b = wid / Nn, i = wid - b * Nn;
    int V = Vbuf[b];
    if (i >= V) return;

    float4 bb = reinterpret_cast<const float4*>(sbox)[b * Nn + i];
    float y1 = bb.x, x1 = bb.y, y2 = bb.z, x2 = bb.w;
    float ar = (y2 - y1) * (x2 - x1);

    unsigned long long* row = mask + ((size_t)(b * Nn) + (size_t)i) * NW;
    int w0 = i >> 6, wlast = (V - 1) >> 6;
    for (int w = w0; w <= wlast; ++w) {
        int j = (w << 6) + lane;
        bool sup = false;
        if (j > i && j < V) {
            float4 cb = reinterpret_cast<const float4*>(sbox)[b * Nn + j];
            float a2 = (cb.z - cb.x) * (cb.w - cb.y);
            float iy = fmaxf(0.0f, fminf(y2, cb.z) - fmaxf(y1, cb.x));
            float ix = fmaxf(0.0f, fminf(x2, cb.w) - fmaxf(x1, cb.y));
            float inter = iy * ix;
            float iou = inter / (ar + a2 - inter + 1e-12f);
            sup = iou > NMSTHR;
        }
        unsigned long long ball = __ballot(sup);
        if (lane == 0) row[w] = ball;
    }
}

// ---------------- Kernel 4: greedy scan, incremental rem[], parallel emit ---
__global__ void __launch_bounds__(64, 1)
k_scan(const unsigned long long* __restrict__ mask,
       const int* __restrict__ Vbuf,
       const uint32_t* __restrict__ sidx,
       const float* __restrict__ refined,
       const float* __restrict__ score,
       const int* __restrict__ cls,
       float* __restrict__ out) {
    int b = blockIdx.x, lane = threadIdx.x;   // 64 threads = 1 wave
    __shared__ unsigned long long rem[NW];
    __shared__ int klist[128];                // capped at MAXI=100 by early break

    int V = Vbuf[b];
    int nblocks = (V + 63) >> 6;              // <= 32 = NW
    const unsigned long long* maskB = mask + (size_t)b * (size_t)Nn * NW;
    const uint32_t*           sidxB = sidx + (size_t)b * Nn;

    if (lane < NW) rem[lane] = 0ull;
    int nkept = 0;

    // prefetch block 0 diagonal words (row base+lane, word 0)
    unsigned long long diag_next = (lane < V) ? maskB[(size_t)lane * NW + 0] : 0ull;

    for (int t = 0; t < nblocks; ++t) {
        int base = t << 6;
        unsigned long long diag = diag_next;
        if (t + 1 < nblocks) {                // prefetch next diagonal early
            int j = base + 64 + lane;
            diag_next = (j < V) ? maskB[(size_t)j * NW + (t + 1)] : 0ull;
        }

        int nb = V - base; if (nb > 64) nb = 64;
        unsigned long long rmw = rem[t];      // broadcast LDS read
        bool alive = (lane < nb) && !((rmw >> lane) & 1ull);
        unsigned long long candm = __ballot(alive);

        while (candm) {                       // one iteration per KEPT box
            int i = __builtin_ctzll(candm);
            if (lane == 0) klist[nkept] = base + i;
            ++nkept;
            if (nkept >= MAXI) break;         // output fully determined

            // merge kept row's FUTURE words into rem (parallel, one load/lane)
            int w = t + 1 + lane;
            if (w < nblocks)
                rem[w] |= maskB[(size_t)(base + i) * NW + w];

            // intra-block suppression by i via its diagonal word
            unsigned long long rowi = __shfl(diag, i, 64);
            alive = alive && !((rowi >> lane) & 1ull);
            candm = __ballot(alive) & ~((2ull << i) - 1ull);
        }
        if (nkept >= MAXI) break;
    }

    int ne = nkept < MAXI ? nkept : MAXI;
    for (int r = lane; r < ne; r += 64) {     // parallel emit
        int gi = b * Nn + (int)sidxB[klist[r]];
        float* orow = out + ((size_t)b * MAXI + r) * 6;
        float4 rf = reinterpret_cast<const float4*>(refined)[gi];
        orow[0] = rf.x;
        orow[1] = rf.y;
        orow[2] = rf.z;
        orow[3] = rf.w;
        orow[4] = (float)cls[gi];
        orow[5] = score[gi];
    }
    for (int tt = ne * 6 + lane; tt < MAXI * 6; tt += 64)
        out[(size_t)b * MAXI * 6 + tt] = 0.0f;
}

// ---------------- launch ----------------------------------------------------
extern "C" void kernel_launch(void* const* d_in, const int* in_sizes, int n_in,
                              void* d_out, int out_size, void* d_ws, size_t ws_size,
                              hipStream_t stream) {
    const float* rois  = (const float*)d_in[0];
    const float* probs = (const float*)d_in[1];
    const float* bbox  = (const float*)d_in[2];
    const float* meta  = (const float*)d_in[3];
    float* out = (float*)d_out;

    const int BN = Bn * Nn;
    char* ws = (char*)d_ws;
    size_t off = 0;
    auto alloc = [&](size_t bytes) {
        void* p = ws + off;
        off += (bytes + 255) & ~(size_t)255;
        return p;
    };
    float*              refined = (float*)              alloc((size_t)BN * 4 * sizeof(float));
    float*              score   = (float*)              alloc((size_t)BN * sizeof(float));
    int*                cls     = (int*)                alloc((size_t)BN * sizeof(int));
    unsigned long long* keys    = (unsigned long long*) alloc((size_t)BN * sizeof(unsigned long long));
    uint32_t*           sidx    = (uint32_t*)           alloc((size_t)BN * sizeof(uint32_t));
    float*              sbox    = (float*)              alloc((size_t)BN * 4 * sizeof(float));
    int*                Vbuf    = (int*)                alloc((size_t)Bn * sizeof(int));
    unsigned long long* mask    = (unsigned long long*) alloc((size_t)BN * NW * sizeof(unsigned long long));
    (void)ws_size; (void)in_sizes; (void)n_in; (void)out_size;

    k_prep<<<BN / PB_ROIS, 256, 0, stream>>>(rois, probs, bbox, meta,
                                             refined, score, cls, keys);
    k_sort<<<Bn, 1024, 0, stream>>>(keys, refined, cls, sidx, sbox, Vbuf);
    k_iou<<<(BN * 64 + 255) / 256, 256, 0, stream>>>(sbox, Vbuf, mask);
    k_scan<<<Bn, 64, 0, stream>>>(mask, Vbuf, sidx, refined, score, cls, out);
}

// Round 7
// 63.692 us; speedup vs baseline: 1.2222x; 1.2222x over previous
//
#include <hip/hip_runtime.h>
#include <stdint.h>

#define Bn 8
#define Nn 2000
#define Cc 81
#define META_STRIDE (12 + Cc)
#define MAXI 100
#define MINCONF 0.7f
#define NMSTHR 0.3f
#define NPAD 2048
#define PB_ROIS 128  // ROIs per k_prep block (16000 / 128 = 125 blocks)
#define PSTRIDE 83   // LDS row stride (81 + 2 pad)

// map float to monotonically ordered uint (descending float == descending uint)
__device__ __forceinline__ uint32_t ford(float f) {
    uint32_t u = __float_as_uint(f);
    return (u & 0x80000000u) ? ~u : (u | 0x80000000u);
}

// ---------------- Kernel 1: LDS-staged argmax, delta apply, clip, sort key --
// (unchanged from round 6 — passed with absmax 0.0)
__global__ void __launch_bounds__(256)
k_prep(const float* __restrict__ rois,
       const float* __restrict__ probs,
       const float* __restrict__ bbox,
       const float* __restrict__ meta,
       float* __restrict__ refined,
       float* __restrict__ score,
       int* __restrict__ cls,
       unsigned long long* __restrict__ keys) {
    __shared__ float sp[PB_ROIS * PSTRIDE];   // 42.5 KB
    int tid  = threadIdx.x;
    int base = blockIdx.x * PB_ROIS;

    const float* gp = probs + (size_t)base * Cc;
    const int total = PB_ROIS * Cc;           // 10368
    int r = tid / Cc, c = tid - r * Cc;
    for (int idx = tid; idx < total; idx += 256) {
        sp[r * PSTRIDE + c] = gp[idx];
        r += 3; c += 13;                      // 256 = 3*81 + 13
        if (c >= Cc) { c -= Cc; r += 1; }
    }
    __syncthreads();

    int row  = tid >> 1;
    int half = tid & 1;
    const float* sr = sp + row * PSTRIDE;
    int   c0 = half ? 41 : 0;
    int   c1 = half ? Cc : 41;
    float v  = sr[c0];
    int   cb = c0;
    for (int cc2 = c0 + 1; cc2 < c1; ++cc2) {
        float x = sr[cc2];
        if (x > v) { v = x; cb = cc2; }       // first max wins within half
    }
    float vo = __shfl_xor(v, 1, 64);
    int   co = __shfl_xor(cb, 1, 64);
    float vA = half ? vo : v;   int cA = half ? co : cb;   // low half
    float vB = half ? v  : vo;  int cB = half ? cb : co;   // high half
    float sbest;  int cbest;
    if (vB > vA) { sbest = vB; cbest = cB; }  // tie -> low half (lower index)
    else         { sbest = vA; cbest = cA; }

    if (half) return;
    int t = base + row;

    float4 d4 = reinterpret_cast<const float4*>(bbox)[(size_t)t * Cc + cbest];
    float dy = d4.x * 0.1f, dx = d4.y * 0.1f, dh = d4.z * 0.2f, dw = d4.w * 0.2f;

    float4 r4 = reinterpret_cast<const float4*>(rois)[t];
    float y1 = r4.x, x1 = r4.y, y2 = r4.z, x2 = r4.w;
    float h = y2 - y1, w = x2 - x1;
    float cy = y1 + 0.5f * h + dy * h;
    float cx = x1 + 0.5f * w + dx * w;
    h = h * expf(dh);
    w = w * expf(dw);
    float ny1 = cy - 0.5f * h, nx1 = cx - 0.5f * w;
    float ny2 = cy + 0.5f * h, nx2 = cx + 0.5f * w;

    int b = t / Nn;
    float sy = meta[4] - 1.0f, sx = meta[5] - 1.0f;
    const float* mb = meta + (size_t)b * META_STRIDE;
    float wy1 = mb[7] / sy;
    float wx1 = mb[8] / sx;
    float wy2 = (mb[9]  - 1.0f) / sy;
    float wx2 = (mb[10] - 1.0f) / sx;

    ny1 = fminf(fmaxf(ny1, wy1), wy2);
    nx1 = fminf(fmaxf(nx1, wx1), wx2);
    ny2 = fminf(fmaxf(ny2, wy1), wy2);
    nx2 = fminf(fmaxf(nx2, wx1), wx2);

    reinterpret_cast<float4*>(refined)[t] = float4{ny1, nx1, ny2, nx2};
    score[t] = sbest;
    cls[t]   = cbest;

    int i = t - b * Nn;
    bool valid = (cbest > 0) && (sbest >= MINCONF);
    float ks = valid ? sbest : -1.0f;
    keys[t] = ((unsigned long long)ford(ks) << 32) |
              (unsigned long long)(0xFFFFFFFFu - (uint32_t)i);
}

// ---------------- Kernel 2: fused sort + on-demand NMS + emit, 1 block/batch
// Bitonic sort of keys in LDS; sorted offset-boxes into LDS; per 64-block of
// sorted candidates: 16 waves recompute ext-suppression (vs <=100 kept boxes)
// and the 64x64 intra-block mask on demand from LDS; wave 0 resolves greedily
// with register-held intra rows; emit first min(100, kept) rows in parallel.
__global__ void __launch_bounds__(1024, 1)
k_batch(const unsigned long long* __restrict__ keys,
        const float* __restrict__ refined,
        const float* __restrict__ score,
        const int* __restrict__ cls,
        float* __restrict__ out) {
    __shared__ unsigned long long sk[NPAD];    // 16 KB
    __shared__ float4 sboxL[Nn];               // 32 KB (sorted offset boxes)
    __shared__ unsigned long long intraw[64];  // intra-block 64x64 mask
    __shared__ unsigned long long extw[16];    // per-wave ext ballot
    __shared__ int klist[128];                 // kept sorted positions (<100)
    __shared__ int sV, sNk;

    int b = blockIdx.x, tid = threadIdx.x;
    int wid = tid >> 6, lane = tid & 63;

    // ---- load + pad keys ----
    const unsigned long long* kb = keys + (size_t)b * Nn;
    for (int t = tid; t < NPAD; t += 1024)
        sk[t] = (t < Nn) ? kb[t] : 0ull;
    if (tid == 0) { sV = 0; sNk = 0; }
    __syncthreads();

    // ---- bitonic sort, descending ----
    for (int k = 2; k <= NPAD; k <<= 1) {
        for (int j = k >> 1; j > 0; j >>= 1) {
            for (int t = tid; t < NPAD; t += 1024) {
                int ixj = t ^ j;
                if (ixj > t) {
                    unsigned long long a = sk[t], c = sk[ixj];
                    bool desc = ((t & k) == 0);
                    if (desc ? (a < c) : (a > c)) { sk[t] = c; sk[ixj] = a; }
                }
            }
            __syncthreads();
        }
    }

    // ---- valid prefix length V ----
    for (int t = tid; t < Nn; t += 1024) {
        bool v0 = (sk[t] >> 63) != 0ull;
        bool v1 = (t + 1 < Nn) ? ((sk[t + 1] >> 63) != 0ull) : false;
        if (v0 && !v1) sV = t + 1;            // single boundary -> single writer
    }
    __syncthreads();
    int V = sV;

    // ---- sorted offset-boxes into LDS (valid prefix only) ----
    for (int t = tid; t < V; t += 1024) {
        uint32_t oi = 0xFFFFFFFFu - (uint32_t)(sk[t] & 0xFFFFFFFFull);
        int gi = b * Nn + (int)oi;
        float off = 4.0f * (float)cls[gi];    // CLASS_OFFSET * class_id
        float4 rf = reinterpret_cast<const float4*>(refined)[gi];
        sboxL[t] = float4{rf.x + off, rf.y + off, rf.z + off, rf.w + off};
    }
    __syncthreads();

    // ---- greedy NMS over 64-candidate blocks ----
    int nblocks = (V + 63) >> 6;
    for (int t = 0; t < nblocks; ++t) {
        int base = t << 6;
        int nb = V - base; if (nb > 64) nb = 64;
        int K = sNk;

        float4 cb = (lane < nb) ? sboxL[base + lane] : float4{0.f, 0.f, 0.f, 0.f};
        float a2 = (cb.z - cb.x) * (cb.w - cb.y);

        // ext: suppression of candidates by earlier kept boxes
        bool supext = false;
        for (int k = wid; k < K; k += 16) {
            float4 kbx = sboxL[klist[k]];
            float ar = (kbx.z - kbx.x) * (kbx.w - kbx.y);
            float iy = fmaxf(0.0f, fminf(kbx.z, cb.z) - fmaxf(kbx.x, cb.x));
            float ix = fmaxf(0.0f, fminf(kbx.w, cb.w) - fmaxf(kbx.y, cb.y));
            float inter = iy * ix;
            float iou = inter / (ar + a2 - inter + 1e-12f);
            supext |= (lane < nb) && (iou > NMSTHR);
        }
        unsigned long long bw = __ballot(supext);
        if (lane == 0) extw[wid] = bw;

        // intra: 64x64 upper-triangular mask, 4 rows per wave
        #pragma unroll
        for (int s = 0; s < 4; ++s) {
            int rr = (wid << 2) + s;          // 0..63, all rows rewritten
            bool sup = false;
            if (rr < nb && lane < nb && lane > rr) {
                float4 rb = sboxL[base + rr];
                float ar = (rb.z - rb.x) * (rb.w - rb.y);
                float iy = fmaxf(0.0f, fminf(rb.z, cb.z) - fmaxf(rb.x, cb.x));
                float ix = fmaxf(0.0f, fminf(rb.w, cb.w) - fmaxf(rb.y, cb.y));
                float inter = iy * ix;
                float iou = inter / (ar + a2 - inter + 1e-12f);
                sup = iou > NMSTHR;
            }
            unsigned long long rb2 = __ballot(sup);
            if (lane == 0) intraw[rr] = rb2;
        }
        __syncthreads();

        if (wid == 0) {                        // wave-0 sequential resolve
            unsigned long long intra_l = intraw[lane];  // row 'lane' in reg
            unsigned long long e = (lane < 16) ? extw[lane] : 0ull;
            #pragma unroll
            for (int m = 8; m >= 1; m >>= 1) e |= __shfl_xor(e, m, 64);
            e = __shfl(e, 0, 64);              // broadcast full OR

            int nk = K;
            bool alive = (lane < nb) && !((e >> lane) & 1ull);
            unsigned long long candm = __ballot(alive);
            while (candm) {                    // one iteration per KEPT box
                int i = __builtin_ctzll(candm);
                if (lane == 0) klist[nk] = base + i;
                ++nk;
                if (nk >= MAXI) break;         // output fully determined
                unsigned long long rowi = __shfl(intra_l, i, 64);
                alive = alive && !((rowi >> lane) & 1ull);
                candm = __ballot(alive) & ~((2ull << i) - 1ull);
            }
            if (lane == 0) sNk = nk;
        }
        __syncthreads();
        if (sNk >= MAXI) break;                // uniform
    }

    // ---- emit first min(100, kept) in sorted order; zero-fill tail ----
    int ne = sNk < MAXI ? sNk : MAXI;
    for (int r = tid; r < ne; r += 1024) {
        int pos = klist[r];
        uint32_t oi = 0xFFFFFFFFu - (uint32_t)(sk[pos] & 0xFFFFFFFFull);
        int gi = b * Nn + (int)oi;
        float4 rf = reinterpret_cast<const float4*>(refined)[gi];
        float* orow = out + ((size_t)b * MAXI + r) * 6;
        orow[0] = rf.x;
        orow[1] = rf.y;
        orow[2] = rf.z;
        orow[3] = rf.w;
        orow[4] = (float)cls[gi];
        orow[5] = score[gi];
    }
    for (int tt = ne * 6 + tid; tt < MAXI * 6; tt += 1024)
        out[(size_t)b * MAXI * 6 + tt] = 0.0f;
}

// ---------------- launch ----------------------------------------------------
extern "C" void kernel_launch(void* const* d_in, const int* in_sizes, int n_in,
                              void* d_out, int out_size, void* d_ws, size_t ws_size,
                              hipStream_t stream) {
    const float* rois  = (const float*)d_in[0];
    const float* probs = (const float*)d_in[1];
    const float* bbox  = (const float*)d_in[2];
    const float* meta  = (const float*)d_in[3];
    float* out = (float*)d_out;

    const int BN = Bn * Nn;
    char* ws = (char*)d_ws;
    size_t off = 0;
    auto alloc = [&](size_t bytes) {
        void* p = ws + off;
        off += (bytes + 255) & ~(size_t)255;
        return p;
    };
    float*              refined = (float*)              alloc((size_t)BN * 4 * sizeof(float));
    float*              score   = (float*)              alloc((size_t)BN * sizeof(float));
    int*                cls     = (int*)                alloc((size_t)BN * sizeof(int));
    unsigned long long* keys    = (unsigned long long*) alloc((size_t)BN * sizeof(unsigned long long));
    (void)ws_size; (void)in_sizes; (void)n_in; (void)out_size;

    k_prep<<<BN / PB_ROIS, 256, 0, stream>>>(rois, probs, bbox, meta,
                                             refined, score, cls, keys);
    k_batch<<<Bn, 1024, 0, stream>>>(keys, refined, score, cls, out);
}

// Round 8
// 45.909 us; speedup vs baseline: 1.6956x; 1.3874x over previous
//
#include <hip/hip_runtime.h>
#include <stdint.h>

#define Bn 8
#define Nn 2000
#define Cc 81
#define META_STRIDE (12 + Cc)
#define MAXI 100
#define MINCONF 0.7f
#define NMSTHR 0.3f
#define NPAD 2048
#define PB_ROIS 128  // ROIs per k_prep block (16000 / 128 = 125 blocks)
#define PSTRIDE 83   // LDS row stride (81 + 2 pad)

// map float to monotonically ordered uint (descending float == descending uint)
__device__ __forceinline__ uint32_t ford(float f) {
    uint32_t u = __float_as_uint(f);
    return (u & 0x80000000u) ? ~u : (u | 0x80000000u);
}

__device__ __forceinline__ unsigned long long shflx64(unsigned long long v, int lx) {
    unsigned int lo = (unsigned int)v, hi = (unsigned int)(v >> 32);
    lo = (unsigned int)__shfl_xor((int)lo, lx, 64);
    hi = (unsigned int)__shfl_xor((int)hi, lx, 64);
    return ((unsigned long long)hi << 32) | lo;
}

// ---------------- Kernel 1: LDS-staged argmax, delta apply, clip, sort key --
// (unchanged from round 6/7 — passed with absmax 0.0)
__global__ void __launch_bounds__(256)
k_prep(const float* __restrict__ rois,
       const float* __restrict__ probs,
       const float* __restrict__ bbox,
       const float* __restrict__ meta,
       float* __restrict__ refined,
       float* __restrict__ score,
       int* __restrict__ cls,
       unsigned long long* __restrict__ keys) {
    __shared__ float sp[PB_ROIS * PSTRIDE];   // 42.5 KB
    int tid  = threadIdx.x;
    int base = blockIdx.x * PB_ROIS;

    const float* gp = probs + (size_t)base * Cc;
    const int total = PB_ROIS * Cc;           // 10368
    int r = tid / Cc, c = tid - r * Cc;
    for (int idx = tid; idx < total; idx += 256) {
        sp[r * PSTRIDE + c] = gp[idx];
        r += 3; c += 13;                      // 256 = 3*81 + 13
        if (c >= Cc) { c -= Cc; r += 1; }
    }
    __syncthreads();

    int row  = tid >> 1;
    int half = tid & 1;
    const float* sr = sp + row * PSTRIDE;
    int   c0 = half ? 41 : 0;
    int   c1 = half ? Cc : 41;
    float v  = sr[c0];
    int   cb = c0;
    for (int cc2 = c0 + 1; cc2 < c1; ++cc2) {
        float x = sr[cc2];
        if (x > v) { v = x; cb = cc2; }       // first max wins within half
    }
    float vo = __shfl_xor(v, 1, 64);
    int   co = __shfl_xor(cb, 1, 64);
    float vA = half ? vo : v;   int cA = half ? co : cb;   // low half
    float vB = half ? v  : vo;  int cB = half ? cb : co;   // high half
    float sbest;  int cbest;
    if (vB > vA) { sbest = vB; cbest = cB; }  // tie -> low half (lower index)
    else         { sbest = vA; cbest = cA; }

    if (half) return;
    int t = base + row;

    float4 d4 = reinterpret_cast<const float4*>(bbox)[(size_t)t * Cc + cbest];
    float dy = d4.x * 0.1f, dx = d4.y * 0.1f, dh = d4.z * 0.2f, dw = d4.w * 0.2f;

    float4 r4 = reinterpret_cast<const float4*>(rois)[t];
    float y1 = r4.x, x1 = r4.y, y2 = r4.z, x2 = r4.w;
    float h = y2 - y1, w = x2 - x1;
    float cy = y1 + 0.5f * h + dy * h;
    float cx = x1 + 0.5f * w + dx * w;
    h = h * expf(dh);
    w = w * expf(dw);
    float ny1 = cy - 0.5f * h, nx1 = cx - 0.5f * w;
    float ny2 = cy + 0.5f * h, nx2 = cx + 0.5f * w;

    int b = t / Nn;
    float sy = meta[4] - 1.0f, sx = meta[5] - 1.0f;
    const float* mb = meta + (size_t)b * META_STRIDE;
    float wy1 = mb[7] / sy;
    float wx1 = mb[8] / sx;
    float wy2 = (mb[9]  - 1.0f) / sy;
    float wx2 = (mb[10] - 1.0f) / sx;

    ny1 = fminf(fmaxf(ny1, wy1), wy2);
    nx1 = fminf(fmaxf(nx1, wx1), wx2);
    ny2 = fminf(fmaxf(ny2, wy1), wy2);
    nx2 = fminf(fmaxf(nx2, wx1), wx2);

    reinterpret_cast<float4*>(refined)[t] = float4{ny1, nx1, ny2, nx2};
    score[t] = sbest;
    cls[t]   = cbest;

    int i = t - b * Nn;
    bool valid = (cbest > 0) && (sbest >= MINCONF);
    float ks = valid ? sbest : -1.0f;
    keys[t] = ((unsigned long long)ford(ks) << 32) |
              (unsigned long long)(0xFFFFFFFFu - (uint32_t)i);
}

// ---------------- Kernel 2: fused register-bitonic sort + NMS + emit --------
// Thread tid holds elements (2*tid, 2*tid+1); wave w owns 128 contiguous
// elements, so all bitonic stages with j<=64 are in-register (shfl_xor /
// in-thread swap). Only j>=128 stages touch LDS (10 of 66). Direction
// desc = ((e0&k)==0) is pair-uniform; lower-index-keeps-max-iff-desc matches
// the reference network, so sorted order is bit-identical to the LDS version.
__global__ void __launch_bounds__(1024, 1)
k_batch(const unsigned long long* __restrict__ keys,
        const float* __restrict__ refined,
        const float* __restrict__ score,
        const int* __restrict__ cls,
        float* __restrict__ out) {
    __shared__ unsigned long long sk[NPAD];    // 16 KB
    __shared__ float4 sboxL[Nn];               // 32 KB (sorted offset boxes)
    __shared__ unsigned long long intraw[64];  // intra-block 64x64 mask
    __shared__ unsigned long long extw[16];    // per-wave ext ballot
    __shared__ int klist[128];                 // kept sorted positions (<100)
    __shared__ int sV, sNk;

    int b = blockIdx.x, tid = threadIdx.x;
    int wid = tid >> 6, lane = tid & 63;
    int e0 = tid << 1;

    // ---- load pair into registers (16B coalesced per lane) ----
    const unsigned long long* kb = keys + (size_t)b * Nn;
    unsigned long long a = (e0     < Nn) ? kb[e0]     : 0ull;
    unsigned long long bv = (e0 + 1 < Nn) ? kb[e0 + 1] : 0ull;
    if (tid == 0) { sV = 0; sNk = 0; }

    // ---- phase A: k = 2..128 entirely in registers (no barriers) ----
    for (int k = 2; k <= 128; k <<= 1) {
        bool desc = ((e0 & k) == 0);
        for (int j = k >> 1; j >= 2; j >>= 1) {
            int lx = j >> 1;
            bool keepmax = (desc == ((lane & lx) == 0));
            unsigned long long oa = shflx64(a, lx);
            unsigned long long ob = shflx64(bv, lx);
            a  = keepmax ? (a  > oa ? a  : oa) : (a  < oa ? a  : oa);
            bv = keepmax ? (bv > ob ? bv : ob) : (bv < ob ? bv : ob);
        }
        bool sw = desc ? (a < bv) : (a > bv);
        if (sw) { unsigned long long t2 = a; a = bv; bv = t2; }
    }
    sk[e0] = a; sk[e0 + 1] = bv;
    __syncthreads();

    // ---- phase B: k = 256..2048; LDS for j>=128, register pass for j<=64 --
    for (int k = 256; k <= NPAD; k <<= 1) {
        for (int j = k >> 1; j >= 128; j >>= 1) {
            #pragma unroll
            for (int rep = 0; rep < 2; ++rep) {
                int t = tid + (rep << 10);
                int ixj = t ^ j;
                if (ixj > t) {
                    unsigned long long x = sk[t], y = sk[ixj];
                    bool desc = ((t & k) == 0);
                    if (desc ? (x < y) : (x > y)) { sk[t] = y; sk[ixj] = x; }
                }
            }
            __syncthreads();
        }
        a = sk[e0]; bv = sk[e0 + 1];
        bool desc = ((e0 & k) == 0);
        #pragma unroll
        for (int lx = 32; lx >= 1; lx >>= 1) {
            bool keepmax = (desc == ((lane & lx) == 0));
            unsigned long long oa = shflx64(a, lx);
            unsigned long long ob = shflx64(bv, lx);
            a  = keepmax ? (a  > oa ? a  : oa) : (a  < oa ? a  : oa);
            bv = keepmax ? (bv > ob ? bv : ob) : (bv < ob ? bv : ob);
        }
        bool sw = desc ? (a < bv) : (a > bv);
        if (sw) { unsigned long long t2 = a; a = bv; bv = t2; }
        sk[e0] = a; sk[e0 + 1] = bv;
        __syncthreads();
    }

    // ---- valid prefix length V ----
    for (int t = tid; t < Nn; t += 1024) {
        bool v0 = (sk[t] >> 63) != 0ull;
        bool v1 = (t + 1 < Nn) ? ((sk[t + 1] >> 63) != 0ull) : false;
        if (v0 && !v1) sV = t + 1;            // single boundary -> single writer
    }
    __syncthreads();
    int V = sV;

    // ---- sorted offset-boxes into LDS (valid prefix only) ----
    for (int t = tid; t < V; t += 1024) {
        uint32_t oi = 0xFFFFFFFFu - (uint32_t)(sk[t] & 0xFFFFFFFFull);
        int gi = b * Nn + (int)oi;
        float off = 4.0f * (float)cls[gi];    // CLASS_OFFSET * class_id
        float4 rf = reinterpret_cast<const float4*>(refined)[gi];
        sboxL[t] = float4{rf.x + off, rf.y + off, rf.z + off, rf.w + off};
    }
    __syncthreads();

    // ---- greedy NMS over 64-candidate blocks ----
    int nblocks = (V + 63) >> 6;
    for (int t = 0; t < nblocks; ++t) {
        int base = t << 6;
        int nb = V - base; if (nb > 64) nb = 64;
        int K = sNk;

        float4 cb = (lane < nb) ? sboxL[base + lane] : float4{0.f, 0.f, 0.f, 0.f};
        float a2 = (cb.z - cb.x) * (cb.w - cb.y);

        // ext: suppression of candidates by earlier kept boxes
        bool supext = false;
        for (int k = wid; k < K; k += 16) {
            float4 kbx = sboxL[klist[k]];
            float ar = (kbx.z - kbx.x) * (kbx.w - kbx.y);
            float iy = fmaxf(0.0f, fminf(kbx.z, cb.z) - fmaxf(kbx.x, cb.x));
            float ix = fmaxf(0.0f, fminf(kbx.w, cb.w) - fmaxf(kbx.y, cb.y));
            float inter = iy * ix;
            float iou = inter / (ar + a2 - inter + 1e-12f);
            supext |= (lane < nb) && (iou > NMSTHR);
        }
        unsigned long long bw = __ballot(supext);
        if (lane == 0) extw[wid] = bw;

        // intra: 64x64 upper-triangular mask, 4 rows per wave
        #pragma unroll
        for (int s = 0; s < 4; ++s) {
            int rr = (wid << 2) + s;          // 0..63, all rows rewritten
            bool sup = false;
            if (rr < nb && lane < nb && lane > rr) {
                float4 rb = sboxL[base + rr];
                float ar = (rb.z - rb.x) * (rb.w - rb.y);
                float iy = fmaxf(0.0f, fminf(rb.z, cb.z) - fmaxf(rb.x, cb.x));
                float ix = fmaxf(0.0f, fminf(rb.w, cb.w) - fmaxf(rb.y, cb.y));
                float inter = iy * ix;
                float iou = inter / (ar + a2 - inter + 1e-12f);
                sup = iou > NMSTHR;
            }
            unsigned long long rb2 = __ballot(sup);
            if (lane == 0) intraw[rr] = rb2;
        }
        __syncthreads();

        if (wid == 0) {                        // wave-0 sequential resolve
            unsigned long long intra_l = intraw[lane];  // row 'lane' in reg
            unsigned long long e = (lane < 16) ? extw[lane] : 0ull;
            #pragma unroll
            for (int m = 8; m >= 1; m >>= 1) e |= __shfl_xor(e, m, 64);
            e = __shfl(e, 0, 64);              // broadcast full OR

            int nk = K;
            bool alive = (lane < nb) && !((e >> lane) & 1ull);
            unsigned long long candm = __ballot(alive);
            while (candm) {                    // one iteration per KEPT box
                int i = __builtin_ctzll(candm);
                if (lane == 0) klist[nk] = base + i;
                ++nk;
                if (nk >= MAXI) break;         // output fully determined
                unsigned long long rowi = __shfl(intra_l, i, 64);
                alive = alive && !((rowi >> lane) & 1ull);
                candm = __ballot(alive) & ~((2ull << i) - 1ull);
            }
            if (lane == 0) sNk = nk;
        }
        __syncthreads();
        if (sNk >= MAXI) break;                // uniform
    }

    // ---- emit first min(100, kept) in sorted order; zero-fill tail ----
    int ne = sNk < MAXI ? sNk : MAXI;
    for (int r = tid; r < ne; r += 1024) {
        int pos = klist[r];
        uint32_t oi = 0xFFFFFFFFu - (uint32_t)(sk[pos] & 0xFFFFFFFFull);
        int gi = b * Nn + (int)oi;
        float4 rf = reinterpret_cast<const float4*>(refined)[gi];
        float* orow = out + ((size_t)b * MAXI + r) * 6;
        orow[0] = rf.x;
        orow[1] = rf.y;
        orow[2] = rf.z;
        orow[3] = rf.w;
        orow[4] = (float)cls[gi];
        orow[5] = score[gi];
    }
    for (int tt = ne * 6 + tid; tt < MAXI * 6; tt += 1024)
        out[(size_t)b * MAXI * 6 + tt] = 0.0f;
}

// ---------------- launch ----------------------------------------------------
extern "C" void kernel_launch(void* const* d_in, const int* in_sizes, int n_in,
                              void* d_out, int out_size, void* d_ws, size_t ws_size,
                              hipStream_t stream) {
    const float* rois  = (const float*)d_in[0];
    const float* probs = (const float*)d_in[1];
    const float* bbox  = (const float*)d_in[2];
    const float* meta  = (const float*)d_in[3];
    float* out = (float*)d_out;

    const int BN = Bn * Nn;
    char* ws = (char*)d_ws;
    size_t off = 0;
    auto alloc = [&](size_t bytes) {
        void* p = ws + off;
        off += (bytes + 255) & ~(size_t)255;
        return p;
    };
    float*              refined = (float*)              alloc((size_t)BN * 4 * sizeof(float));
    float*              score   = (float*)              alloc((size_t)BN * sizeof(float));
    int*                cls     = (int*)                alloc((size_t)BN * sizeof(int));
    unsigned long long* keys    = (unsigned long long*) alloc((size_t)BN * sizeof(unsigned long long));
    (void)ws_size; (void)in_sizes; (void)n_in; (void)out_size;

    k_prep<<<BN / PB_ROIS, 256, 0, stream>>>(rois, probs, bbox, meta,
                                             refined, score, cls, keys);
    k_batch<<<Bn, 1024, 0, stream>>>(keys, refined, score, cls, out);
}